// Round 2
// baseline (654.537 us; speedup 1.0000x reference)
//
#include <hip/hip_runtime.h>
#include <hip/hip_bf16.h>

#define NN 96
#define GBLK 48
#define JROWS 2
#define NITER 50
#define MAGIC 0xC0FFEEu

__device__ __forceinline__ float bf2f(__hip_bfloat16 v) { return __bfloat162float(v); }

// dtype-agnostic load: f32 flag is wave-uniform
__device__ __forceinline__ float LD(const void* p, int i, bool f32) {
  return f32 ? ((const float*)p)[i]
             : __bfloat162float(((const __hip_bfloat16*)p)[i]);
}

// Monotonic-counter device-wide barrier.
__device__ __forceinline__ void gbar(uint32_t* ctr, uint32_t target) {
  __threadfence();
  __syncthreads();
  if (threadIdx.x == 0) {
    __hip_atomic_fetch_add(ctr, 1u, __ATOMIC_ACQ_REL, __HIP_MEMORY_SCOPE_AGENT);
    while (__hip_atomic_load(ctr, __ATOMIC_ACQUIRE, __HIP_MEMORY_SCOPE_AGENT) < target) {
      __builtin_amdgcn_s_sleep(1);
    }
    __threadfence();
  }
  __syncthreads();
}

__global__ __launch_bounds__(256, 1) void gvae_kernel(
    const void* __restrict__ ge,
    const void* __restrict__ adj,
    const void* __restrict__ W1,
    const void* __restrict__ b1,
    const void* __restrict__ W2,
    const void* __restrict__ b2,
    const void* __restrict__ W3,
    const void* __restrict__ b3,
    void* __restrict__ out,
    float* __restrict__ ws)
{
  __shared__ __align__(16) float t2s[NN * NN];      // 36 KB
  __shared__ __align__(16) float xs[JROWS * NN];
  __shared__ __align__(16) float Ds[JROWS * NN];
  __shared__ __align__(16) float parts[8 * JROWS * NN];
  __shared__ float ges[256];
  __shared__ float frs[NN];
  __shared__ float dRs[NN];
  __shared__ float h1s[250];
  __shared__ float h2s[100];
  __shared__ int   nbr[JROWS * NN];
  __shared__ int   ncnt[JROWS];
  __shared__ float f_own[JROWS];
  __shared__ float red[4];
  __shared__ float s_scale;

  const int tid = threadIdx.x;
  const int blk = blockIdx.x;

  // ---- dtype sniff: read 256 B of W1/W3 as bf16; float32 buffers show
  // huge/NaN garbage at mantissa-half positions (P(miss) ~ 1e-16). ----
  float sv = (tid < 128) ? bf2f(((const __hip_bfloat16*)W1)[tid])
                         : bf2f(((const __hip_bfloat16*)W3)[tid - 128]);
  const bool isf32 = __syncthreads_or(!(fabsf(sv) < 1e4f)) != 0;

  uint32_t* ctr    = (uint32_t*)ws;
  uint32_t* ready  = (uint32_t*)ws + 1;
  float*    normsq = ws + 32;            // 50 slots
  float*    lg2    = ws + 96;            // 48 x 128 padded sigmoid outputs
  float*    M0     = ws + 6272;
  float*    M1     = ws + 6272 + NN * NN;

  // ---- P0: init ws (block 0), everyone waits for magic ----
  if (blk == 0) {
    if (tid < NITER) normsq[tid] = 0.0f;
    __syncthreads();
    if (tid == 0) {
      __hip_atomic_store(ctr, 0u, __ATOMIC_RELAXED, __HIP_MEMORY_SCOPE_AGENT);
      __threadfence();
      __hip_atomic_store(ready, MAGIC, __ATOMIC_RELEASE, __HIP_MEMORY_SCOPE_AGENT);
    }
  }
  if (tid == 0) {
    while (__hip_atomic_load(ready, __ATOMIC_ACQUIRE, __HIP_MEMORY_SCOPE_AGENT) != MAGIC) {
      __builtin_amdgcn_s_sleep(1);
    }
    __threadfence();
  }
  __syncthreads();

  // ---- P1: MLP layers 1-2, redundant per block ----
  ges[tid] = LD(ge, tid, isf32);
  __syncthreads();
  if (tid < 250) {
    float acc = LD(b1, tid, isf32);
    for (int e = 0; e < 256; ++e)
      acc += ges[e] * LD(W1, e * 250 + tid, isf32);
    h1s[tid] = acc;
  }
  __syncthreads();
  if (tid < 100) {
    float acc = LD(b2, tid, isf32);
    for (int k = 0; k < 250; ++k)
      acc += h1s[k] * LD(W2, k * 100 + tid, isf32);
    h2s[tid] = fmaxf(acc, 0.0f);
  }
  __syncthreads();

  // ---- P2: sigmoid layer (grid-distributed) + own adjacency rows ----
  if (tid < 97) {
    int o = blk * 97 + tid;
    float acc = LD(b3, o, isf32);
    for (int k = 0; k < 100; ++k)
      acc += h2s[k] * LD(W3, k * 4656 + o, isf32);
    lg2[blk * 128 + tid] = 1.0f / (1.0f + expf(-acc));
  }
  if (tid < JROWS) {
    int ig = blk * JROWS + tid;
    float fsum = 1.0f;  // diag of ori forced to 1
    int c = 0;
    for (int j2 = 0; j2 < NN; ++j2) {
      if (j2 == ig) continue;
      float v = LD(adj, ig * NN + j2, isf32);
      fsum += v;
      if (v > 0.5f) nbr[tid * NN + (c++)] = j2;
    }
    ncnt[tid] = c;
    f_own[tid] = fsum;
  }
  if (tid < JROWS * NN) xs[tid] = 1.0f / 96.0f;   // ||x0|| = 1 exactly

  gbar(ctr, 1 * GBLK);

  // ---- P3: recon -> fr, dR -> t2, D (redundant per block) ----
  for (int e = tid; e < NN * NN; e += 256) {
    int a = e / NN, b = e % NN;
    int i = min(a, b), j = max(a, b);
    int k = i * NN - (i * (i - 1)) / 2 + (j - i);   // row-major triu index
    t2s[e] = __hip_atomic_load(&lg2[(k / 97) * 128 + (k % 97)],
                               __ATOMIC_RELAXED, __HIP_MEMORY_SCOPE_AGENT);
  }
  __syncthreads();
  if (tid < NN) {
    float s = 0.0f;
    for (int b = 0; b < NN; ++b) s += t2s[tid * NN + b];
    frs[tid] = s;
    dRs[tid] = t2s[tid * NN + tid];
  }
  __syncthreads();
  for (int e = tid; e < NN * NN; e += 256) {
    int a = e / NN, b = e % NN;
    t2s[e] = (a == b) ? 0.0f : t2s[e] * dRs[a] * dRs[b];
  }
  if (tid < JROWS * NN) {
    int il = tid / NN, a = tid % NN;
    Ds[tid] = dRs[a] / (fabsf(f_own[il] - frs[a]) + 1.0f);
  }
  __syncthreads();

  // ---- main mpm loop: one device barrier per iteration ----
  for (int it = 0; it < NITER; ++it) {
    float* Mw = (it & 1) ? M1 : M0;

    // Phase A: M[j][a] = max_b x[j][b]*t2[a][b] for this block's 2 rows.
    if (tid < 192) {
      int aq = tid % 24;
      int e8 = tid / 24;
      int b0 = e8 * 12;
      float xr0[12], xr1[12];
#pragma unroll
      for (int c4 = 0; c4 < 3; ++c4) {
        float4 v0 = *(const float4*)&xs[b0 + 4 * c4];
        float4 v1 = *(const float4*)&xs[NN + b0 + 4 * c4];
        xr0[4 * c4 + 0] = v0.x; xr0[4 * c4 + 1] = v0.y;
        xr0[4 * c4 + 2] = v0.z; xr0[4 * c4 + 3] = v0.w;
        xr1[4 * c4 + 0] = v1.x; xr1[4 * c4 + 1] = v1.y;
        xr1[4 * c4 + 2] = v1.z; xr1[4 * c4 + 3] = v1.w;
      }
      float4 a0 = make_float4(0.f, 0.f, 0.f, 0.f);   // products >= 0
      float4 a1 = make_float4(0.f, 0.f, 0.f, 0.f);
#pragma unroll
      for (int c = 0; c < 12; ++c) {
        float4 t = *(const float4*)&t2s[(b0 + c) * NN + 4 * aq];
        a0.x = fmaxf(a0.x, xr0[c] * t.x); a0.y = fmaxf(a0.y, xr0[c] * t.y);
        a0.z = fmaxf(a0.z, xr0[c] * t.z); a0.w = fmaxf(a0.w, xr0[c] * t.w);
        a1.x = fmaxf(a1.x, xr1[c] * t.x); a1.y = fmaxf(a1.y, xr1[c] * t.y);
        a1.z = fmaxf(a1.z, xr1[c] * t.z); a1.w = fmaxf(a1.w, xr1[c] * t.w);
      }
      *(float4*)&parts[(e8 * 2 + 0) * NN + 4 * aq] = a0;
      *(float4*)&parts[(e8 * 2 + 1) * NN + 4 * aq] = a1;
    }
    __syncthreads();
    if (tid < 192) {
      int jl = tid / NN, a = tid % NN;
      float m = parts[jl * NN + a];
#pragma unroll
      for (int e = 1; e < 8; ++e) m = fmaxf(m, parts[(e * 2 + jl) * NN + a]);
      Mw[(blk * JROWS + jl) * NN + a] = m;
    }

    gbar(ctr, (uint32_t)((it + 2) * GBLK));

    // Phase C: u[i][a] = scale * (x[i][a]*D[i][a] + sum_{j in N(i)} M[j][a])
    if (tid == 0) {
      s_scale = (it == 0) ? 1.0f
          : rsqrtf(__hip_atomic_load(&normsq[it - 1], __ATOMIC_RELAXED,
                                     __HIP_MEMORY_SCOPE_AGENT));
    }
    __syncthreads();
    float scale = s_scale;
    float nsq = 0.0f;
    if (tid < 192) {
      int il = tid / NN, a = tid % NN;
      float acc = xs[tid] * Ds[tid];
      int cnt = ncnt[il];
      const int* nb = &nbr[il * NN];
      for (int c = 0; c < cnt; ++c) {
        int j = nb[c];
        acc += __hip_atomic_load(&Mw[j * NN + a], __ATOMIC_RELAXED,
                                 __HIP_MEMORY_SCOPE_AGENT);
      }
      float u = scale * acc;
      xs[tid] = u;
      nsq = u * u;
    }
#pragma unroll
    for (int off = 32; off > 0; off >>= 1) nsq += __shfl_down(nsq, off);
    if ((tid & 63) == 0) red[tid >> 6] = nsq;
    __syncthreads();
    if (tid == 0) {
      float t = red[0] + red[1] + red[2] + red[3];
      atomicAdd(&normsq[it], t);
    }
    __syncthreads();
  }

  // ---- final exact normalization + store (dtype per sniff) ----
  gbar(ctr, (uint32_t)((NITER + 2) * GBLK));
  if (tid == 0) {
    s_scale = rsqrtf(__hip_atomic_load(&normsq[NITER - 1], __ATOMIC_RELAXED,
                                       __HIP_MEMORY_SCOPE_AGENT));
  }
  __syncthreads();
  if (tid < JROWS * NN) {
    int il = tid / NN, a = tid % NN;
    int o = (blk * JROWS + il) * NN + a;
    float v = s_scale * xs[tid];
    if (isf32) ((float*)out)[o] = v;
    else       ((__hip_bfloat16*)out)[o] = __float2bfloat16(v);
  }
}

extern "C" void kernel_launch(void* const* d_in, const int* in_sizes, int n_in,
                              void* d_out, int out_size, void* d_ws, size_t ws_size,
                              hipStream_t stream) {
  (void)in_sizes; (void)n_in; (void)out_size; (void)ws_size;
  hipLaunchKernelGGL(gvae_kernel, dim3(GBLK), dim3(256), 0, stream,
                     d_in[0], d_in[1], d_in[3], d_in[4], d_in[5], d_in[6],
                     d_in[7], d_in[8], d_out, (float*)d_ws);
}

// Round 3
// 596.175 us; speedup vs baseline: 1.0979x; 1.0979x over previous
//
#include <hip/hip_runtime.h>
#include <hip/hip_bf16.h>

#define NN 96
#define GBLK 48
#define JROWS 2
#define NITER 50
#define MAGIC 0xC0FFEEu

__device__ __forceinline__ float bf2f(__hip_bfloat16 v) { return __bfloat162float(v); }

// dtype-agnostic load: f32 flag is wave-uniform
__device__ __forceinline__ float LD(const void* p, int i, bool f32) {
  return f32 ? ((const float*)p)[i]
             : __bfloat162float(((const __hip_bfloat16*)p)[i]);
}

// Monotonic-counter device-wide barrier. Writer side: plain stores +
// __threadfence (writeback) + release RMW. Reader side: acquire spin +
// __threadfence (emits buffer_inv -> CU L1 + XCD L2 invalidated), so PLAIN
// loads of barrier-protected data are coherent afterwards.
__device__ __forceinline__ void gbar(uint32_t* ctr, uint32_t target) {
  __threadfence();
  __syncthreads();
  if (threadIdx.x == 0) {
    __hip_atomic_fetch_add(ctr, 1u, __ATOMIC_ACQ_REL, __HIP_MEMORY_SCOPE_AGENT);
    while (__hip_atomic_load(ctr, __ATOMIC_ACQUIRE, __HIP_MEMORY_SCOPE_AGENT) < target) {
      __builtin_amdgcn_s_sleep(1);
    }
    __threadfence();
  }
  __syncthreads();
}

__global__ __launch_bounds__(256, 1) void gvae_kernel(
    const void* __restrict__ ge,
    const void* __restrict__ adj,
    const void* __restrict__ W1,
    const void* __restrict__ b1,
    const void* __restrict__ W2,
    const void* __restrict__ b2,
    const void* __restrict__ W3,
    const void* __restrict__ b3,
    void* __restrict__ out,
    float* __restrict__ ws)
{
  __shared__ __align__(16) float t2s[NN * NN];      // 36 KB
  __shared__ __align__(16) float Ms[NN * NN];       // 36 KB broadcast of M
  __shared__ __align__(16) float xs[JROWS * NN];
  __shared__ __align__(16) float Ds[JROWS * NN];
  __shared__ __align__(16) float parts[8 * JROWS * NN];
  __shared__ float ges[256];
  __shared__ float frs[NN];
  __shared__ float dRs[NN];
  __shared__ float h1s[250];
  __shared__ float h2s[100];
  __shared__ int   nbr[JROWS * NN];
  __shared__ int   ncnt[JROWS];
  __shared__ float f_own[JROWS];
  __shared__ float red[4];
  __shared__ float s_scale;

  const int tid = threadIdx.x;
  const int blk = blockIdx.x;

  // ---- dtype sniff (wave-uniform; inputs fixed -> graph-safe) ----
  float sv = (tid < 128) ? bf2f(((const __hip_bfloat16*)W1)[tid])
                         : bf2f(((const __hip_bfloat16*)W3)[tid - 128]);
  const bool isf32 = __syncthreads_or(!(fabsf(sv) < 1e4f)) != 0;

  uint32_t* ctr    = (uint32_t*)ws;
  uint32_t* ready  = (uint32_t*)ws + 1;
  float*    normsq = ws + 32;            // 50 slots
  float*    lg2    = ws + 96;            // 48 x 128 padded sigmoid outputs
  float*    M0     = ws + 6272;          // 16B aligned
  float*    M1     = ws + 6272 + NN * NN;

  // ---- P0: init ws (block 0), everyone waits for magic ----
  if (blk == 0) {
    if (tid < NITER) normsq[tid] = 0.0f;
    __syncthreads();
    if (tid == 0) {
      __hip_atomic_store(ctr, 0u, __ATOMIC_RELAXED, __HIP_MEMORY_SCOPE_AGENT);
      __threadfence();
      __hip_atomic_store(ready, MAGIC, __ATOMIC_RELEASE, __HIP_MEMORY_SCOPE_AGENT);
    }
  }
  if (tid == 0) {
    while (__hip_atomic_load(ready, __ATOMIC_ACQUIRE, __HIP_MEMORY_SCOPE_AGENT) != MAGIC) {
      __builtin_amdgcn_s_sleep(1);
    }
    __threadfence();
  }
  __syncthreads();

  // ---- P1: MLP layers 1-2, redundant per block ----
  ges[tid] = LD(ge, tid, isf32);
  __syncthreads();
  if (tid < 250) {
    float acc = LD(b1, tid, isf32);
    for (int e = 0; e < 256; ++e)
      acc += ges[e] * LD(W1, e * 250 + tid, isf32);
    h1s[tid] = acc;
  }
  __syncthreads();
  if (tid < 100) {
    float acc = LD(b2, tid, isf32);
    for (int k = 0; k < 250; ++k)
      acc += h1s[k] * LD(W2, k * 100 + tid, isf32);
    h2s[tid] = fmaxf(acc, 0.0f);
  }
  __syncthreads();

  // ---- P2: sigmoid layer (grid-distributed) + own adjacency rows ----
  if (tid < 97) {
    int o = blk * 97 + tid;
    float acc = LD(b3, o, isf32);
    for (int k = 0; k < 100; ++k)
      acc += h2s[k] * LD(W3, k * 4656 + o, isf32);
    lg2[blk * 128 + tid] = 1.0f / (1.0f + expf(-acc));
  }
  if (tid < JROWS) {
    int ig = blk * JROWS + tid;
    float fsum = 1.0f;  // diag of ori forced to 1
    int c = 0;
    for (int j2 = 0; j2 < NN; ++j2) {
      if (j2 == ig) continue;
      float v = LD(adj, ig * NN + j2, isf32);
      fsum += v;
      if (v > 0.5f) nbr[tid * NN + (c++)] = j2;
    }
    ncnt[tid] = c;
    f_own[tid] = fsum;
  }
  if (tid < JROWS * NN) xs[tid] = 1.0f / 96.0f;   // ||x0|| = 1 exactly

  gbar(ctr, 1 * GBLK);

  // ---- P3: recon -> fr, dR -> t2, D (plain loads: gbar gave acquire) ----
  for (int e = tid; e < NN * NN; e += 256) {
    int a = e / NN, b = e % NN;
    int i = min(a, b), j = max(a, b);
    int k = i * NN - (i * (i - 1)) / 2 + (j - i);   // row-major triu index
    t2s[e] = lg2[(k / 97) * 128 + (k % 97)];
  }
  __syncthreads();
  if (tid < NN) {
    float s = 0.0f;
    for (int b = 0; b < NN; ++b) s += t2s[tid * NN + b];
    frs[tid] = s;
    dRs[tid] = t2s[tid * NN + tid];
  }
  __syncthreads();
  for (int e = tid; e < NN * NN; e += 256) {
    int a = e / NN, b = e % NN;
    t2s[e] = (a == b) ? 0.0f : t2s[e] * dRs[a] * dRs[b];
  }
  if (tid < JROWS * NN) {
    int il = tid / NN, a = tid % NN;
    Ds[tid] = dRs[a] / (fabsf(f_own[il] - frs[a]) + 1.0f);
  }
  __syncthreads();

  // ---- main mpm loop: one device barrier per iteration ----
  for (int it = 0; it < NITER; ++it) {
    float* Mw = (it & 1) ? M1 : M0;

    // Phase A: M[j][a] = max_b x[j][b]*t2[a][b] for this block's 2 rows.
    if (tid < 192) {
      int aq = tid % 24;
      int e8 = tid / 24;
      int b0 = e8 * 12;
      float xr0[12], xr1[12];
#pragma unroll
      for (int c4 = 0; c4 < 3; ++c4) {
        float4 v0 = *(const float4*)&xs[b0 + 4 * c4];
        float4 v1 = *(const float4*)&xs[NN + b0 + 4 * c4];
        xr0[4 * c4 + 0] = v0.x; xr0[4 * c4 + 1] = v0.y;
        xr0[4 * c4 + 2] = v0.z; xr0[4 * c4 + 3] = v0.w;
        xr1[4 * c4 + 0] = v1.x; xr1[4 * c4 + 1] = v1.y;
        xr1[4 * c4 + 2] = v1.z; xr1[4 * c4 + 3] = v1.w;
      }
      float4 a0 = make_float4(0.f, 0.f, 0.f, 0.f);   // products >= 0
      float4 a1 = make_float4(0.f, 0.f, 0.f, 0.f);
#pragma unroll
      for (int c = 0; c < 12; ++c) {
        float4 t = *(const float4*)&t2s[(b0 + c) * NN + 4 * aq];
        a0.x = fmaxf(a0.x, xr0[c] * t.x); a0.y = fmaxf(a0.y, xr0[c] * t.y);
        a0.z = fmaxf(a0.z, xr0[c] * t.z); a0.w = fmaxf(a0.w, xr0[c] * t.w);
        a1.x = fmaxf(a1.x, xr1[c] * t.x); a1.y = fmaxf(a1.y, xr1[c] * t.y);
        a1.z = fmaxf(a1.z, xr1[c] * t.z); a1.w = fmaxf(a1.w, xr1[c] * t.w);
      }
      *(float4*)&parts[(e8 * 2 + 0) * NN + 4 * aq] = a0;
      *(float4*)&parts[(e8 * 2 + 1) * NN + 4 * aq] = a1;
    }
    __syncthreads();
    if (tid < 192) {
      int jl = tid / NN, a = tid % NN;
      float m = parts[jl * NN + a];
#pragma unroll
      for (int e = 1; e < 8; ++e) m = fmaxf(m, parts[(e * 2 + jl) * NN + a]);
      Mw[(blk * JROWS + jl) * NN + a] = m;
    }

    gbar(ctr, (uint32_t)((it + 2) * GBLK));

    // Broadcast full M into LDS: 9 independent float4 loads per thread,
    // all in flight -> one memory latency instead of a serialized chain.
    {
      const float4* Mr4 = (const float4*)Mw;
      float4* Ms4 = (float4*)Ms;
#pragma unroll
      for (int e = 0; e < 9; ++e) {
        int idx = tid + 256 * e;   // 9*256 = 2304 = NN*NN/4 exactly
        Ms4[idx] = Mr4[idx];
      }
    }
    if (tid == 0) {
      s_scale = (it == 0) ? 1.0f : rsqrtf(normsq[it - 1]);
    }
    __syncthreads();

    // Phase C: u[i][a] = scale * (x[i][a]*D[i][a] + sum_{j in N(i)} M[j][a])
    float scale = s_scale;
    float nsq = 0.0f;
    if (tid < 192) {
      int il = tid / NN, a = tid % NN;
      float acc = xs[tid] * Ds[tid];
      int cnt = ncnt[il];
      const int* nb = &nbr[il * NN];
      for (int c = 0; c < cnt; ++c) {
        acc += Ms[nb[c] * NN + a];       // LDS, conflict-free, pipelined
      }
      float u = scale * acc;
      xs[tid] = u;
      nsq = u * u;
    }
#pragma unroll
    for (int off = 32; off > 0; off >>= 1) nsq += __shfl_down(nsq, off);
    if ((tid & 63) == 0) red[tid >> 6] = nsq;
    __syncthreads();
    if (tid == 0) {
      float t = red[0] + red[1] + red[2] + red[3];
      atomicAdd(&normsq[it], t);
    }
    __syncthreads();
  }

  // ---- final exact normalization + store ----
  gbar(ctr, (uint32_t)((NITER + 2) * GBLK));
  if (tid == 0) {
    s_scale = rsqrtf(normsq[NITER - 1]);
  }
  __syncthreads();
  if (tid < JROWS * NN) {
    int il = tid / NN, a = tid % NN;
    int o = (blk * JROWS + il) * NN + a;
    float v = s_scale * xs[tid];
    if (isf32) ((float*)out)[o] = v;
    else       ((__hip_bfloat16*)out)[o] = __float2bfloat16(v);
  }
}

extern "C" void kernel_launch(void* const* d_in, const int* in_sizes, int n_in,
                              void* d_out, int out_size, void* d_ws, size_t ws_size,
                              hipStream_t stream) {
  (void)in_sizes; (void)n_in; (void)out_size; (void)ws_size;
  hipLaunchKernelGGL(gvae_kernel, dim3(GBLK), dim3(256), 0, stream,
                     d_in[0], d_in[1], d_in[3], d_in[4], d_in[5], d_in[6],
                     d_in[7], d_in[8], d_out, (float*)d_ws);
}

// Round 4
// 581.180 us; speedup vs baseline: 1.1262x; 1.0258x over previous
//
#include <hip/hip_runtime.h>
#include <hip/hip_bf16.h>

#define NN 96
#define GBLK 48
#define JROWS 2
#define NITER 50
#define MAGIC 0xC0FFEEu

__device__ __forceinline__ float bf2f(__hip_bfloat16 v) { return __bfloat162float(v); }

// dtype-agnostic load: f32 flag is wave-uniform
__device__ __forceinline__ float LD(const void* p, int i, bool f32) {
  return f32 ? ((const float*)p)[i]
             : __bfloat162float(((const __hip_bfloat16*)p)[i]);
}

// Relaxed agent-scope accessors: compile to global_load/store ... sc1
// (bypass non-coherent XCD L2, served at MALL = agent coherence point).
// No buffer_wbl2 / buffer_inv cache maintenance is ever generated.
__device__ __forceinline__ float ldA(const float* p) {
  return __hip_atomic_load(p, __ATOMIC_RELAXED, __HIP_MEMORY_SCOPE_AGENT);
}
__device__ __forceinline__ void stA(float* p, float v) {
  __hip_atomic_store(p, v, __ATOMIC_RELAXED, __HIP_MEMORY_SCOPE_AGENT);
}
__device__ __forceinline__ unsigned long long ldA64(const unsigned long long* p) {
  return __hip_atomic_load(p, __ATOMIC_RELAXED, __HIP_MEMORY_SCOPE_AGENT);
}

// Fence-free device barrier. Every wave drains its own vmcnt (so this
// block's sc1 stores are acked at MALL) before the block arrives; thread 0
// does a relaxed RMW arrival + relaxed spin. No cache maintenance: all
// cross-block data is itself sc1-scoped, so no invalidates are needed.
__device__ __forceinline__ void gbar(uint32_t* ctr, uint32_t target) {
  asm volatile("s_waitcnt vmcnt(0)" ::: "memory");
  __syncthreads();
  if (threadIdx.x == 0) {
    __hip_atomic_fetch_add(ctr, 1u, __ATOMIC_RELAXED, __HIP_MEMORY_SCOPE_AGENT);
    while (__hip_atomic_load(ctr, __ATOMIC_RELAXED, __HIP_MEMORY_SCOPE_AGENT) < target) {
      __builtin_amdgcn_s_sleep(1);
    }
  }
  __syncthreads();
}

__global__ __launch_bounds__(256, 1) void gvae_kernel(
    const void* __restrict__ ge,
    const void* __restrict__ adj,
    const void* __restrict__ W1,
    const void* __restrict__ b1,
    const void* __restrict__ W2,
    const void* __restrict__ b2,
    const void* __restrict__ W3,
    const void* __restrict__ b3,
    void* __restrict__ out,
    float* __restrict__ ws)
{
  __shared__ __align__(16) float t2s[NN * NN];      // 36 KB
  __shared__ __align__(16) float Ms[NN * NN];       // 36 KB broadcast of M
  __shared__ __align__(16) float xs[JROWS * NN];
  __shared__ __align__(16) float Ds[JROWS * NN];
  __shared__ __align__(16) float parts[8 * JROWS * NN];
  __shared__ float ges[256];
  __shared__ float frs[NN];
  __shared__ float dRs[NN];
  __shared__ float h1s[250];
  __shared__ float h2s[100];
  __shared__ int   nbr[JROWS * NN];
  __shared__ int   ncnt[JROWS];
  __shared__ float f_own[JROWS];
  __shared__ float red[4];
  __shared__ float s_scale;

  const int tid = threadIdx.x;
  const int blk = blockIdx.x;

  // ---- dtype sniff (wave-uniform; inputs fixed -> graph-safe) ----
  float sv = (tid < 128) ? bf2f(((const __hip_bfloat16*)W1)[tid])
                         : bf2f(((const __hip_bfloat16*)W3)[tid - 128]);
  const bool isf32 = __syncthreads_or(!(fabsf(sv) < 1e4f)) != 0;

  uint32_t* ctr    = (uint32_t*)ws;
  uint32_t* ready  = (uint32_t*)ws + 1;
  float*    normsq = ws + 32;            // 50 slots
  float*    lg2    = ws + 96;            // 48 x 128 padded sigmoid outputs
  float*    M0     = ws + 6272;          // 16B aligned
  float*    M1     = ws + 6272 + NN * NN;

  // ---- P0: init ws (block 0), everyone waits for magic ----
  if (blk == 0) {
    if (tid < NITER) stA(&normsq[tid], 0.0f);
    asm volatile("s_waitcnt vmcnt(0)" ::: "memory");
    __syncthreads();
    if (tid == 0) {
      __hip_atomic_store(ctr, 0u, __ATOMIC_RELAXED, __HIP_MEMORY_SCOPE_AGENT);
      asm volatile("s_waitcnt vmcnt(0)" ::: "memory");  // ctr at MALL first
      __hip_atomic_store(ready, MAGIC, __ATOMIC_RELAXED, __HIP_MEMORY_SCOPE_AGENT);
    }
  }
  if (tid == 0) {
    while (__hip_atomic_load(ready, __ATOMIC_RELAXED, __HIP_MEMORY_SCOPE_AGENT) != MAGIC) {
      __builtin_amdgcn_s_sleep(1);
    }
  }
  __syncthreads();

  // ---- P1: MLP layers 1-2, redundant per block ----
  ges[tid] = LD(ge, tid, isf32);
  __syncthreads();
  if (tid < 250) {
    float acc = LD(b1, tid, isf32);
    for (int e = 0; e < 256; ++e)
      acc += ges[e] * LD(W1, e * 250 + tid, isf32);
    h1s[tid] = acc;
  }
  __syncthreads();
  if (tid < 100) {
    float acc = LD(b2, tid, isf32);
    for (int k = 0; k < 250; ++k)
      acc += h1s[k] * LD(W2, k * 100 + tid, isf32);
    h2s[tid] = fmaxf(acc, 0.0f);
  }
  __syncthreads();

  // ---- P2: sigmoid layer (grid-distributed, sc1 stores) + adjacency ----
  if (tid < 97) {
    int o = blk * 97 + tid;
    float acc = LD(b3, o, isf32);
    for (int k = 0; k < 100; ++k)
      acc += h2s[k] * LD(W3, k * 4656 + o, isf32);
    stA(&lg2[blk * 128 + tid], 1.0f / (1.0f + expf(-acc)));
  }
  if (tid < JROWS) {
    int ig = blk * JROWS + tid;
    float fsum = 1.0f;  // diag of ori forced to 1
    int c = 0;
    for (int j2 = 0; j2 < NN; ++j2) {
      if (j2 == ig) continue;
      float v = LD(adj, ig * NN + j2, isf32);
      fsum += v;
      if (v > 0.5f) nbr[tid * NN + (c++)] = j2;
    }
    ncnt[tid] = c;
    f_own[tid] = fsum;
  }
  if (tid < JROWS * NN) xs[tid] = 1.0f / 96.0f;   // ||x0|| = 1 exactly

  gbar(ctr, 1 * GBLK);

  // ---- P3: recon -> fr, dR -> t2, D (sc1 reads of lg2) ----
  for (int e = tid; e < NN * NN; e += 256) {
    int a = e / NN, b = e % NN;
    int i = min(a, b), j = max(a, b);
    int k = i * NN - (i * (i - 1)) / 2 + (j - i);   // row-major triu index
    t2s[e] = ldA(&lg2[(k / 97) * 128 + (k % 97)]);
  }
  __syncthreads();
  if (tid < NN) {
    float s = 0.0f;
    for (int b = 0; b < NN; ++b) s += t2s[tid * NN + b];
    frs[tid] = s;
    dRs[tid] = t2s[tid * NN + tid];
  }
  __syncthreads();
  for (int e = tid; e < NN * NN; e += 256) {
    int a = e / NN, b = e % NN;
    t2s[e] = (a == b) ? 0.0f : t2s[e] * dRs[a] * dRs[b];
  }
  if (tid < JROWS * NN) {
    int il = tid / NN, a = tid % NN;
    Ds[tid] = dRs[a] / (fabsf(f_own[il] - frs[a]) + 1.0f);
  }
  __syncthreads();

  // ---- main mpm loop: one fence-free device barrier per iteration ----
  for (int it = 0; it < NITER; ++it) {
    float* Mw = (it & 1) ? M1 : M0;

    // Phase A: M[j][a] = max_b x[j][b]*t2[a][b] for this block's 2 rows.
    if (tid < 192) {
      int aq = tid % 24;
      int e8 = tid / 24;
      int b0 = e8 * 12;
      float xr0[12], xr1[12];
#pragma unroll
      for (int c4 = 0; c4 < 3; ++c4) {
        float4 v0 = *(const float4*)&xs[b0 + 4 * c4];
        float4 v1 = *(const float4*)&xs[NN + b0 + 4 * c4];
        xr0[4 * c4 + 0] = v0.x; xr0[4 * c4 + 1] = v0.y;
        xr0[4 * c4 + 2] = v0.z; xr0[4 * c4 + 3] = v0.w;
        xr1[4 * c4 + 0] = v1.x; xr1[4 * c4 + 1] = v1.y;
        xr1[4 * c4 + 2] = v1.z; xr1[4 * c4 + 3] = v1.w;
      }
      float4 a0 = make_float4(0.f, 0.f, 0.f, 0.f);   // products >= 0
      float4 a1 = make_float4(0.f, 0.f, 0.f, 0.f);
#pragma unroll
      for (int c = 0; c < 12; ++c) {
        float4 t = *(const float4*)&t2s[(b0 + c) * NN + 4 * aq];
        a0.x = fmaxf(a0.x, xr0[c] * t.x); a0.y = fmaxf(a0.y, xr0[c] * t.y);
        a0.z = fmaxf(a0.z, xr0[c] * t.z); a0.w = fmaxf(a0.w, xr0[c] * t.w);
        a1.x = fmaxf(a1.x, xr1[c] * t.x); a1.y = fmaxf(a1.y, xr1[c] * t.y);
        a1.z = fmaxf(a1.z, xr1[c] * t.z); a1.w = fmaxf(a1.w, xr1[c] * t.w);
      }
      *(float4*)&parts[(e8 * 2 + 0) * NN + 4 * aq] = a0;
      *(float4*)&parts[(e8 * 2 + 1) * NN + 4 * aq] = a1;
    }
    __syncthreads();
    if (tid < 192) {
      int jl = tid / NN, a = tid % NN;
      float m = parts[jl * NN + a];
#pragma unroll
      for (int e = 1; e < 8; ++e) m = fmaxf(m, parts[(e * 2 + jl) * NN + a]);
      stA(&Mw[(blk * JROWS + jl) * NN + a], m);     // sc1: straight to MALL
    }

    gbar(ctr, (uint32_t)((it + 2) * GBLK));

    // Broadcast full M into LDS: 18 independent dwordx2 sc1 loads/thread,
    // all in flight -> ~one MALL latency total.
    {
      const unsigned long long* Mr8 = (const unsigned long long*)Mw;
      unsigned long long* Ms8 = (unsigned long long*)Ms;
#pragma unroll
      for (int e = 0; e < 18; ++e) {
        int idx = tid + 256 * e;   // 18*256 = 4608 = NN*NN/2 exactly
        Ms8[idx] = ldA64(&Mr8[idx]);
      }
    }
    if (tid == 0) {
      s_scale = (it == 0) ? 1.0f : rsqrtf(ldA(&normsq[it - 1]));
    }
    __syncthreads();

    // Phase C: u[i][a] = scale * (x[i][a]*D[i][a] + sum_{j in N(i)} M[j][a])
    float scale = s_scale;
    float nsq = 0.0f;
    if (tid < 192) {
      int il = tid / NN, a = tid % NN;
      float acc = xs[tid] * Ds[tid];
      int cnt = ncnt[il];
      const int* nb = &nbr[il * NN];
      for (int c = 0; c < cnt; ++c) {
        acc += Ms[nb[c] * NN + a];       // LDS, conflict-free, pipelined
      }
      float u = scale * acc;
      xs[tid] = u;
      nsq = u * u;
    }
#pragma unroll
    for (int off = 32; off > 0; off >>= 1) nsq += __shfl_down(nsq, off);
    if ((tid & 63) == 0) red[tid >> 6] = nsq;
    __syncthreads();
    if (tid == 0) {
      float t = red[0] + red[1] + red[2] + red[3];
      __hip_atomic_fetch_add(&normsq[it], t, __ATOMIC_RELAXED,
                             __HIP_MEMORY_SCOPE_AGENT);
    }
    __syncthreads();
  }

  // ---- final exact normalization + store ----
  gbar(ctr, (uint32_t)((NITER + 2) * GBLK));
  if (tid == 0) {
    s_scale = rsqrtf(ldA(&normsq[NITER - 1]));
  }
  __syncthreads();
  if (tid < JROWS * NN) {
    int il = tid / NN, a = tid % NN;
    int o = (blk * JROWS + il) * NN + a;
    float v = s_scale * xs[tid];
    if (isf32) ((float*)out)[o] = v;
    else       ((__hip_bfloat16*)out)[o] = __float2bfloat16(v);
  }
}

extern "C" void kernel_launch(void* const* d_in, const int* in_sizes, int n_in,
                              void* d_out, int out_size, void* d_ws, size_t ws_size,
                              hipStream_t stream) {
  (void)in_sizes; (void)n_in; (void)out_size; (void)ws_size;
  hipLaunchKernelGGL(gvae_kernel, dim3(GBLK), dim3(256), 0, stream,
                     d_in[0], d_in[1], d_in[3], d_in[4], d_in[5], d_in[6],
                     d_in[7], d_in[8], d_out, (float*)d_ws);
}